// Round 8
// baseline (857.813 us; speedup 1.0000x reference)
//
#include <hip/hip_runtime.h>
#include <hip/hip_bf16.h>
#include <cstdint>
#include <cstddef>

typedef __hip_bfloat16 bf16;
typedef float  floatx4 __attribute__((ext_vector_type(4)));
typedef __bf16 bf16x8  __attribute__((ext_vector_type(8)));

typedef __attribute__((address_space(1))) void as1_void;
typedef __attribute__((address_space(3))) void as3_void;

constexpr int Bn = 4, Ln = 2048, Cn = 1024;
constexpr int GRID = 512;    // 2 blocks/CU co-resident (enforced by launch_bounds)

__device__ __forceinline__ void store_one(float* p, float v) { *p = v; }
__device__ __forceinline__ void store_one(bf16*  p, float v) { *p = __float2bfloat16(v); }

// ---------------------------------------------------------------------------
// Device-scope grid barrier. R7 post-mortem: spinning on atomicAdd(cnt,0)
// (an RMW) serializes 512 waves at the coherence point and stretches every
// barrier to tens of µs. Spin on a device-scope atomic LOAD instead —
// read-shared at the LLC, no RMW queue. Arrival remains one RMW per block.
// ---------------------------------------------------------------------------
__device__ __forceinline__ void gbar(int* cnt, int target)
{
    __syncthreads();
    if (threadIdx.x == 0) {
        __threadfence();                       // release this block's writes
        __hip_atomic_fetch_add(cnt, 1, __ATOMIC_ACQ_REL, __HIP_MEMORY_SCOPE_AGENT);
        while (__hip_atomic_load(cnt, __ATOMIC_ACQUIRE, __HIP_MEMORY_SCOPE_AGENT) < target)
            __builtin_amdgcn_s_sleep(8);
        __threadfence();                       // acquire other blocks' writes
    }
    __syncthreads();
}

// ---------------------------------------------------------------------------
// Core bf16 BT-GEMM tile (unchanged; R2 note: no LDS swizzle — 4/ds_read_b128
// conflicts are intrinsic; R4/R5 note: callers keep XCD pinning via
// blockIdx%8-invariant index maps).
// ---------------------------------------------------------------------------
template <typename OutT>
__device__ __forceinline__ void gemm_core(
    bf16* smem,
    const bf16* __restrict__ A, const bf16* __restrict__ B, OutT* __restrict__ C,
    int m0, int n0, int Keff, int lda, int ldb, int ldc, float cscale)
{
    const int tid  = threadIdx.x;
    const int lane = tid & 63;
    const int quad = lane >> 4;
    const int lr   = lane & 15;
    const int wave = tid >> 6;
    const int wm   = (wave >> 1) * 64;
    const int wn   = (wave & 1) * 64;

    floatx4 acc[4][4];
#pragma unroll
    for (int i = 0; i < 4; ++i)
#pragma unroll
        for (int j = 0; j < 4; ++j) { floatx4 z = {0.f, 0.f, 0.f, 0.f}; acc[i][j] = z; }

    const bf16* gbase[4];
    int ldsoff[4];
#pragma unroll
    for (int it = 0; it < 4; ++it) {
        int chunk = it * 256 + tid;
        ldsoff[it] = __builtin_amdgcn_readfirstlane((chunk & ~63) * 16);
        int kc = chunk & 3;
        if (chunk < 512) {
            int m = chunk >> 2;
            gbase[it] = A + (size_t)(m0 + m) * lda + kc * 8;
        } else {
            int c2 = chunk - 512;
            int n = c2 >> 2;
            gbase[it] = B + (size_t)(n0 + n) * ldb + kc * 8;
        }
    }

    for (int k0 = 0; k0 < Keff; k0 += 32) {
        __syncthreads();
#pragma unroll
        for (int it = 0; it < 4; ++it) {
            uintptr_t ga = (uintptr_t)(gbase[it] + k0);
            uintptr_t la = (uintptr_t)((char*)smem + ldsoff[it]);
            __builtin_amdgcn_global_load_lds((const as1_void*)ga, (as3_void*)la, 16, 0, 0);
        }
        __syncthreads();

        const bf16* As = smem;
        const bf16* Bs = smem + 128 * 32;
        bf16x8 afrag[4], bfrag[4];
#pragma unroll
        for (int i = 0; i < 4; ++i)
            afrag[i] = *(const bf16x8*)(As + (size_t)(wm + i * 16 + lr) * 32 + quad * 8);
#pragma unroll
        for (int j = 0; j < 4; ++j)
            bfrag[j] = *(const bf16x8*)(Bs + (size_t)(wn + j * 16 + lr) * 32 + quad * 8);
#pragma unroll
        for (int i = 0; i < 4; ++i)
#pragma unroll
            for (int j = 0; j < 4; ++j)
                acc[i][j] = __builtin_amdgcn_mfma_f32_16x16x32_bf16(afrag[i], bfrag[j], acc[i][j], 0, 0, 0);
    }

#pragma unroll
    for (int i = 0; i < 4; ++i) {
        int row = m0 + wm + i * 16 + quad * 4;
#pragma unroll
        for (int j = 0; j < 4; ++j) {
            int col = n0 + wn + j * 16 + lr;
            OutT* cp = C + (size_t)row * ldc + col;
#pragma unroll
            for (int r = 0; r < 4; ++r)
                store_one(cp + (size_t)r * ldc, acc[i][j][r] * cscale);
        }
    }
}

__device__ __forceinline__ float waveMax(float x) {
#pragma unroll
    for (int o = 32; o > 0; o >>= 1) x = fmaxf(x, __shfl_xor(x, o, 64));
    return x;
}
__device__ __forceinline__ float waveSum(float x) {
#pragma unroll
    for (int o = 32; o > 0; o >>= 1) x += __shfl_xor(x, o, 64);
    return x;
}

struct Params {
    const float *X, *Wqkv, *Wo;
    bf16 *Xb, *Wqkb, *WvT, *Wob, *W2, *QK, *VWT, *S;
    float *out;
    int *bar;
};

// ---------------------------------------------------------------------------
// Persistent kernel, phases separated by gbar():
// P0: cast Wqk/Wo + transpose-cast Wv -> WvT
// P1: W2 = Wo·Wv (blocks 0..63)  ||  cast X (blocks 64..511)
// P2: QK (1024) + VWT (512) = 1536 tiles, exactly 3/block
// P3: S = (Q·K^T)/32, triangular 544 tiles (batch pinned to XCD pair)
// P4: causal softmax in place
// P5: out = P·VW (K clamped to m0+128), fp32
// ---------------------------------------------------------------------------
__global__ __launch_bounds__(256, 2) void mega(Params p)
{
    const int blk = blockIdx.x;
    const int tid = threadIdx.x;
    __shared__ __align__(16) bf16 smem[2 * 128 * 32];   // 16 KB, reused per phase

    // ---- P0: weight casts --------------------------------------------------
    for (int u = blk * 256 + tid; u < 524288 + 262144; u += GRID * 256) {
        const float* src; bf16* dst; int off;
        if (u < 524288) { src = p.Wqkv; dst = p.Wqkb; off = u; }
        else            { src = p.Wo;   dst = p.Wob;  off = u - 524288; }
        float4 f = ((const float4*)src)[off];
        bf16 o0 = __float2bfloat16(f.x), o1 = __float2bfloat16(f.y);
        bf16 o2 = __float2bfloat16(f.z), o3 = __float2bfloat16(f.w);
        ushort4 uu;
        uu.x = *(unsigned short*)&o0; uu.y = *(unsigned short*)&o1;
        uu.z = *(unsigned short*)&o2; uu.w = *(unsigned short*)&o3;
        *(ushort4*)(dst + (size_t)off * 4) = uu;
    }
    {
        float* t = (float*)smem;                 // 32x33 floats
        const float* Wv = p.Wqkv + (size_t)2048 * 1024;
        int xcol = tid & 31, y0 = tid >> 5;
        for (int tt = blk; tt < 1024; tt += GRID) {
            int c0 = (tt & 31) * 32, r0 = (tt >> 5) * 32;
            __syncthreads();
#pragma unroll
            for (int q = 0; q < 4; ++q) {
                int y = y0 + 8 * q;
                t[y * 33 + xcol] = Wv[(size_t)(r0 + y) * 1024 + c0 + xcol];
            }
            __syncthreads();
#pragma unroll
            for (int q = 0; q < 4; ++q) {
                int mloc = y0 + 8 * q;
                p.WvT[(size_t)(c0 + mloc) * 1024 + r0 + xcol] =
                    __float2bfloat16(t[xcol * 33 + mloc]);
            }
        }
    }
    gbar(p.bar, 1 * GRID);

    // ---- P1: W2 (64 tiles) || X cast ---------------------------------------
    if (blk < 64) {
        int m0 = (blk & 7) * 128, n0 = (blk >> 3) * 128;
        gemm_core<bf16>(smem, p.Wob, p.WvT, p.W2, m0, n0, 1024, 1024, 1024, 1024, 1.0f);
    } else {
        for (int u = (blk - 64) * 256 + tid; u < 2097152; u += 448 * 256) {
            float4 f = ((const float4*)p.X)[u];
            bf16 o0 = __float2bfloat16(f.x), o1 = __float2bfloat16(f.y);
            bf16 o2 = __float2bfloat16(f.z), o3 = __float2bfloat16(f.w);
            ushort4 uu;
            uu.x = *(unsigned short*)&o0; uu.y = *(unsigned short*)&o1;
            uu.z = *(unsigned short*)&o2; uu.w = *(unsigned short*)&o3;
            *(ushort4*)(p.Xb + (size_t)u * 4) = uu;
        }
    }
    gbar(p.bar, 2 * GRID);

    // ---- P2: QK (1024) + VWT (512), exactly 3 tiles/block ------------------
    for (int t = blk; t < 1536; t += GRID) {
        if (t < 1024) {
            int m0 = (t & 63) * 128, n0 = (t >> 6) * 128;
            gemm_core<bf16>(smem, p.Xb, p.Wqkb, p.QK, m0, n0, 1024, 1024, 1024, 2048, 1.0f);
        } else {
            int v = t - 1024;                    // 0..511
            int m0 = (v >> 6) * 128, n0 = (v & 63) * 128;   // Xb n-tile XCD-pinned
            gemm_core<bf16>(smem, p.W2, p.Xb, p.VWT, m0, n0, 1024, 1024, 1024, 8192, 1.0f);
        }
    }
    gbar(p.bar, 3 * GRID);

    // ---- P3: S triangular (544 tiles; s%8 = 2b+p pins batch to XCD pair) ---
    for (int s = blk; s < 544; s += GRID) {
        int b = (s & 7) >> 1;
        int pp = s & 1;
        int tt = (s >> 3) * 2 + pp;              // 0..135
        int ti = (int)((sqrtf(8.f * tt + 1.f) - 1.f) * 0.5f);
        while ((ti + 1) * (ti + 2) / 2 <= tt) ++ti;
        while (ti * (ti + 1) / 2 > tt) --ti;
        int tj = tt - ti * (ti + 1) / 2;
        const bf16* Aq = p.QK + (long long)b * Ln * 2048;
        const bf16* Bk = Aq + 1024;
        bf16* Sb = p.S + (long long)b * Ln * Ln;
        gemm_core<bf16>(smem, Aq, Bk, Sb, ti * 128, tj * 128, 1024, 2048, 2048, Ln, 0.03125f);
    }
    gbar(p.bar, 4 * GRID);

    // ---- P4: causal softmax in place (one wave per row) --------------------
    {
        const int wave = tid >> 6, lane = tid & 63;
        for (int g = blk; g < 2048; g += GRID) {
            const int row = g * 4 + wave;
            const int q = row & (Ln - 1);
            bf16* Srow = p.S + (long long)row * Ln;
            const int kmax = ((q >> 7) + 1) << 7;
            const int nv = (kmax + 511) >> 9;

            float x[4][8];
            float m = -1e30f;
            for (int it = 0; it < nv; ++it) {
                int c0 = it * 512 + lane * 8;
                bf16x8 v = *(const bf16x8*)(Srow + c0);
#pragma unroll
                for (int e = 0; e < 8; ++e) {
                    float f = (float)v[e];
                    f = (c0 + e <= q) ? f : -1e30f;
                    x[it][e] = f;
                    m = fmaxf(m, f);
                }
            }
            m = waveMax(m);
            float sum = 0.f;
            for (int it = 0; it < nv; ++it)
#pragma unroll
                for (int e = 0; e < 8; ++e) {
                    float ex = (x[it][e] > -1e29f) ? __expf(x[it][e] - m) : 0.f;
                    x[it][e] = ex;
                    sum += ex;
                }
            sum = waveSum(sum);
            float inv = 1.f / sum;
            for (int it = 0; it < nv; ++it) {
                bf16x8 o;
#pragma unroll
                for (int e = 0; e < 8; ++e) o[e] = (__bf16)(x[it][e] * inv);
                *(bf16x8*)(Srow + it * 512 + lane * 8) = o;
            }
        }
    }
    gbar(p.bar, 5 * GRID);

    // ---- P5: out = P·VW (512 tiles, 1/block; batch pinned to XCD pair) -----
    {
        int r = blk & 7, q2 = blk >> 3;
        int b = r >> 1, pp = r & 1;
        int mt = 15 - (q2 >> 2), nt = pp + 2 * (q2 & 3);
        int m0 = mt * 128, n0 = nt * 128;
        const bf16* Pp = p.S + (long long)b * Ln * Ln;
        const bf16* Bv = p.VWT + b * Ln;
        float* Co = p.out + (long long)b * Ln * Cn;
        gemm_core<float>(smem, Pp, Bv, Co, m0, n0, m0 + 128, Ln, 8192, Cn, 1.0f);
    }
}

// ---------------------------------------------------------------------------
extern "C" void kernel_launch(void* const* d_in, const int* in_sizes, int n_in,
                              void* d_out, int out_size, void* d_ws, size_t ws_size,
                              hipStream_t stream)
{
    const float* X    = (const float*)d_in[0];   // (B,L,C)
    const float* Wqkv = (const float*)d_in[1];   // (3C,C)
    const float* Wout = (const float*)d_in[2];   // (C,C)
    float* out = (float*)d_out;                  // (B,L,C) fp32

    char* ws = (char*)d_ws;
    const size_t MiB = 1024ull * 1024ull;
    Params p;
    p.X    = X;  p.Wqkv = Wqkv;  p.Wo = Wout;  p.out = out;
    p.Xb   = (bf16*)(ws + 0);                // 16 MiB
    p.QK   = (bf16*)(ws + 16 * MiB);         // 32 MiB
    p.VWT  = (bf16*)(ws + 48 * MiB);         // 16 MiB (1024 x 8192, ld 8192)
    p.S    = (bf16*)(ws + 64 * MiB);         // 32 MiB (P in place)
    p.Wqkb = (bf16*)(ws + 96 * MiB);         // 4 MiB
    p.WvT  = (bf16*)(ws + 100 * MiB);        // 2 MiB
    p.Wob  = (bf16*)(ws + 102 * MiB);        // 2 MiB
    p.W2   = (bf16*)(ws + 104 * MiB);        // 2 MiB
    p.bar  = (int*)(ws + 106 * MiB);         // barrier counter (zeroed below)

    hipMemsetAsync(p.bar, 0, 256, stream);   // ws re-poisoned 0xAA before each call
    mega<<<dim3(GRID), dim3(256), 0, stream>>>(p);
}

// Round 9
// 281.057 us; speedup vs baseline: 3.0521x; 3.0521x over previous
//
#include <hip/hip_runtime.h>
#include <hip/hip_bf16.h>
#include <cstdint>
#include <cstddef>

typedef __hip_bfloat16 bf16;
typedef float  floatx4 __attribute__((ext_vector_type(4)));
typedef __bf16 bf16x8  __attribute__((ext_vector_type(8)));

typedef __attribute__((address_space(1))) void as1_void;
typedef __attribute__((address_space(3))) void as3_void;

constexpr int Bn = 4, Ln = 2048, Cn = 1024;

__device__ __forceinline__ void store_one(float* p, float v) { *p = v; }
__device__ __forceinline__ void store_one(bf16*  p, float v) { *p = __float2bfloat16(v); }

// ---------------------------------------------------------------------------
// Core bf16 BT-GEMM tile: C[m0..+128][n0..+128] = cscale * sum_k A[m][k]*B[n][k]
// 256 thr / 4 waves, each wave 64x64 via 4x4 mfma_f32_16x16x32_bf16.
// BK=64 (R9): halves the per-iteration vmcnt(0)+s_barrier drains vs BK=32
// (the ~20% structural stall), LDS 32 KB keeps 3 blocks/CU (m132's BK=128
// trap was the drop to 2). Keff must be a multiple of 64.
// NOTE (R2): no LDS swizzle — 4/ds_read_b128 conflicts are intrinsic.
// NOTE (R4/R5): callers keep XCD pinning via blockIdx%8-invariant maps.
// NOTE (R7/R8): persistent-kernel grid barriers cost ≫ launch gaps. Abandoned.
// ---------------------------------------------------------------------------
template <typename OutT>
__device__ __forceinline__ void gemm_core(
    const bf16* __restrict__ A, const bf16* __restrict__ B, OutT* __restrict__ C,
    int m0, int n0, int Keff, int lda, int ldb, int ldc, float cscale)
{
    __shared__ __align__(16) bf16 smem[2 * 128 * 64];   // As (16KB) then Bs (16KB)

    const int tid  = threadIdx.x;
    const int lane = tid & 63;
    const int quad = lane >> 4;
    const int lr   = lane & 15;
    const int wave = tid >> 6;
    const int wm   = (wave >> 1) * 64;
    const int wn   = (wave & 1) * 64;

    floatx4 acc[4][4];
#pragma unroll
    for (int i = 0; i < 4; ++i)
#pragma unroll
        for (int j = 0; j < 4; ++j) { floatx4 z = {0.f, 0.f, 0.f, 0.f}; acc[i][j] = z; }

    // staging: 2048 16B chunks / iter; chunk = it*256 + tid, LDS lane-linear.
    // 64 bf16 per row = 8 chunks; A rows then B rows.
    const bf16* gbase[8];
    int ldsoff[8];
#pragma unroll
    for (int it = 0; it < 8; ++it) {
        int chunk = it * 256 + tid;
        ldsoff[it] = __builtin_amdgcn_readfirstlane((chunk & ~63) * 16);
        int seg = chunk & 7;
        if (chunk < 1024) {
            int m = chunk >> 3;
            gbase[it] = A + (size_t)(m0 + m) * lda + seg * 8;
        } else {
            int c2 = chunk - 1024;
            int n = c2 >> 3;
            gbase[it] = B + (size_t)(n0 + n) * ldb + seg * 8;
        }
    }

    for (int k0 = 0; k0 < Keff; k0 += 64) {
        __syncthreads();
#pragma unroll
        for (int it = 0; it < 8; ++it) {
            uintptr_t ga = (uintptr_t)(gbase[it] + k0);
            uintptr_t la = (uintptr_t)((char*)smem + ldsoff[it]);
            __builtin_amdgcn_global_load_lds((const as1_void*)ga, (as3_void*)la, 16, 0, 0);
        }
        __syncthreads();

        const bf16* As = smem;
        const bf16* Bs = smem + 128 * 64;
#pragma unroll
        for (int u = 0; u < 2; ++u) {
            const int ko = u * 32 + quad * 8;
            bf16x8 afrag[4], bfrag[4];
#pragma unroll
            for (int i = 0; i < 4; ++i)
                afrag[i] = *(const bf16x8*)(As + (size_t)(wm + i * 16 + lr) * 64 + ko);
#pragma unroll
            for (int j = 0; j < 4; ++j)
                bfrag[j] = *(const bf16x8*)(Bs + (size_t)(wn + j * 16 + lr) * 64 + ko);
#pragma unroll
            for (int i = 0; i < 4; ++i)
#pragma unroll
                for (int j = 0; j < 4; ++j)
                    acc[i][j] = __builtin_amdgcn_mfma_f32_16x16x32_bf16(afrag[i], bfrag[j], acc[i][j], 0, 0, 0);
        }
    }

    // epilogue: C/D layout col=lane&15, row=quad*4+r  (m89-verified)
#pragma unroll
    for (int i = 0; i < 4; ++i) {
        int row = m0 + wm + i * 16 + quad * 4;
#pragma unroll
        for (int j = 0; j < 4; ++j) {
            int col = n0 + wn + j * 16 + lr;
            OutT* cp = C + (size_t)row * ldc + col;
#pragma unroll
            for (int r = 0; r < 4; ++r)
                store_one(cp + (size_t)r * ldc, acc[i][j][r] * cscale);
        }
    }
}

// ---------------------------------------------------------------------------
// g1: blocks [0,64)    -> W2 = Wo·Wv   (1024x1024, K=1024)  [A=Wob, B=WvT]
//     blocks [64,1088) -> QK = Xb·Wqk^T (8192x2048, K=1024)
// ---------------------------------------------------------------------------
__global__ __launch_bounds__(256)
void g1_w2_qk(const bf16* __restrict__ Xb, const bf16* __restrict__ Wqkb,
              const bf16* __restrict__ Wob, const bf16* __restrict__ WvT,
              bf16* __restrict__ QK, bf16* __restrict__ W2)
{
    int i = blockIdx.x;
    if (i < 64) {
        int m0 = (i & 7) * 128, n0 = (i >> 3) * 128;
        gemm_core<bf16>(Wob, WvT, W2, m0, n0, 1024, 1024, 1024, 1024, 1.0f);
    } else {
        int j = i - 64;
        int m0 = (j & 63) * 128, n0 = (j >> 6) * 128;
        gemm_core<bf16>(Xb, Wqkb, QK, m0, n0, 1024, 1024, 1024, 2048, 1.0f);
    }
}

// ---------------------------------------------------------------------------
// g2: blocks [0,512)    -> VWT = W2·Xb^T (1024x8192, K=1024, ldc 8192)
//        n0 = (i&63): blocks sharing an Xb n-tile sit at stride 64 -> same XCD.
//     blocks [512,1056) -> S = (Q·K^T)/32, triangular tiles, 136/batch.
//        s%8 = 2b+p pins batch b to XCD pair {2b,2b+1}.
// ---------------------------------------------------------------------------
__global__ __launch_bounds__(256)
void g2_vwt_s(const bf16* __restrict__ W2, const bf16* __restrict__ Xb,
              const bf16* __restrict__ QK, bf16* __restrict__ VWT,
              bf16* __restrict__ S)
{
    int i = blockIdx.x;
    if (i < 512) {
        int m0 = (i >> 6) * 128, n0 = (i & 63) * 128;
        gemm_core<bf16>(W2, Xb, VWT, m0, n0, 1024, 1024, 1024, 8192, 1.0f);
    } else {
        int s = i - 512;                 // 0..543
        int b = (s & 7) >> 1;
        int p = s & 1;
        int t = (s >> 3) * 2 + p;        // 0..135
        int ti = (int)((sqrtf(8.f * t + 1.f) - 1.f) * 0.5f);
        while ((ti + 1) * (ti + 2) / 2 <= t) ++ti;
        while (ti * (ti + 1) / 2 > t) --ti;
        int tj = t - ti * (ti + 1) / 2;
        const bf16* Aq = QK + (long long)b * Ln * 2048;
        const bf16* Bk = Aq + 1024;
        bf16* Sb = S + (long long)b * Ln * Ln;
        gemm_core<bf16>(Aq, Bk, Sb, ti * 128, tj * 128, 1024, 2048, 2048, Ln, 0.03125f);
    }
}

// ---------------------------------------------------------------------------
// g3: out = P · VW  (per batch, K clamped to m0+128), fp32 out.
// XCD = i%8 = 2b+p; mt = 15-(q>>2) heavy-first; P m-tile shared by 4 blocks.
// ---------------------------------------------------------------------------
__global__ __launch_bounds__(256)
void g3_out(const bf16* __restrict__ P, const bf16* __restrict__ VWT,
            float* __restrict__ out)
{
    int i = blockIdx.x;                  // 512
    int r = i & 7, q = i >> 3;
    int b = r >> 1, p = r & 1;
    int mt = 15 - (q >> 2), nt = p + 2 * (q & 3);
    int m0 = mt * 128, n0 = nt * 128;
    const bf16* Pp = P + (long long)b * Ln * Ln;
    const bf16* Bv = VWT + b * Ln;
    float* Co = out + (long long)b * Ln * Cn;
    gemm_core<float>(Pp, Bv, Co, m0, n0, m0 + 128, Ln, 8192, Cn, 1.0f);
}

// ---------------------------------------------------------------------------
// Causal softmax on bf16 S in place (scale folded into g2). One WAVE per row,
// bf16x8 vector loads/stores, wave-level reductions only (no barriers).
// ---------------------------------------------------------------------------
__device__ __forceinline__ float waveMax(float x) {
#pragma unroll
    for (int o = 32; o > 0; o >>= 1) x = fmaxf(x, __shfl_xor(x, o, 64));
    return x;
}
__device__ __forceinline__ float waveSum(float x) {
#pragma unroll
    for (int o = 32; o > 0; o >>= 1) x += __shfl_xor(x, o, 64);
    return x;
}

__global__ __launch_bounds__(256)
void softmax_causal(bf16* __restrict__ S)
{
    const int wave = threadIdx.x >> 6, lane = threadIdx.x & 63;
    const int row = blockIdx.x * 4 + wave;       // 0..8191 = b*L + q
    const int q = row & (Ln - 1);
    bf16* Srow = S + (long long)row * Ln;
    const int kmax = ((q >> 7) + 1) << 7;
    const int nv = (kmax + 511) >> 9;            // 1..4 chunks of 512 cols

    float x[4][8];
    float m = -1e30f;
    for (int it = 0; it < nv; ++it) {
        int c0 = it * 512 + lane * 8;
        bf16x8 v = *(const bf16x8*)(Srow + c0);
#pragma unroll
        for (int e = 0; e < 8; ++e) {
            float f = (float)v[e];
            f = (c0 + e <= q) ? f : -1e30f;
            x[it][e] = f;
            m = fmaxf(m, f);
        }
    }
    m = waveMax(m);
    float s = 0.f;
    for (int it = 0; it < nv; ++it)
#pragma unroll
        for (int e = 0; e < 8; ++e) {
            float ex = (x[it][e] > -1e29f) ? __expf(x[it][e] - m) : 0.f;
            x[it][e] = ex;
            s += ex;
        }
    s = waveSum(s);
    float inv = 1.f / s;
    for (int it = 0; it < nv; ++it) {
        bf16x8 o;
#pragma unroll
        for (int e = 0; e < 8; ++e) o[e] = (__bf16)(x[it][e] * inv);
        *(bf16x8*)(Srow + it * 512 + lane * 8) = o;
    }
}

// ---------------------------------------------------------------------------
// cast_all: blocks [0,11264)   element-wise fp32->bf16 (X, Wqk rows, Wout)
//           blocks [11264,12288) transpose-cast Wv (1024x1024) -> WvT
// ---------------------------------------------------------------------------
__global__ __launch_bounds__(256)
void cast_all(const float* __restrict__ X, const float* __restrict__ Wqkv,
              const float* __restrict__ Wo,
              bf16* __restrict__ Xb, bf16* __restrict__ Wqkb,
              bf16* __restrict__ Wob, bf16* __restrict__ WvT)
{
    int blk = blockIdx.x;
    if (blk < 11264) {
        int i = blk * 256 + threadIdx.x;
        const float* src; bf16* dst; int off;
        if (i < 2097152)                 { src = X;    dst = Xb;   off = i; }
        else if (i < 2097152 + 524288)   { src = Wqkv; dst = Wqkb; off = i - 2097152; }
        else                             { src = Wo;   dst = Wob;  off = i - 2621440; }
        float4 f = ((const float4*)src)[off];
        bf16 o0 = __float2bfloat16(f.x), o1 = __float2bfloat16(f.y);
        bf16 o2 = __float2bfloat16(f.z), o3 = __float2bfloat16(f.w);
        ushort4 u;
        u.x = *(unsigned short*)&o0; u.y = *(unsigned short*)&o1;
        u.z = *(unsigned short*)&o2; u.w = *(unsigned short*)&o3;
        *(ushort4*)(dst + (size_t)off * 4) = u;
    } else {
        __shared__ float t[32][33];
        int tt = blk - 11264;
        int c0 = (tt & 31) * 32;         // col tile in Wv
        int r0 = (tt >> 5) * 32;         // row tile in Wv
        const float* Wv = Wqkv + 2048 * 1024;
        int xcol = threadIdx.x & 31, y0 = threadIdx.x >> 5;
#pragma unroll
        for (int p = 0; p < 4; ++p) {
            int y = y0 + 8 * p;
            t[y][xcol] = Wv[(size_t)(r0 + y) * 1024 + c0 + xcol];
        }
        __syncthreads();
#pragma unroll
        for (int p = 0; p < 4; ++p) {
            int mloc = y0 + 8 * p;       // WvT[c0+mloc][r0+xcol] = Wv[r0+xcol][c0+mloc]
            WvT[(size_t)(c0 + mloc) * 1024 + r0 + xcol] = __float2bfloat16(t[xcol][mloc]);
        }
    }
}

// ---------------------------------------------------------------------------
extern "C" void kernel_launch(void* const* d_in, const int* in_sizes, int n_in,
                              void* d_out, int out_size, void* d_ws, size_t ws_size,
                              hipStream_t stream)
{
    const float* X    = (const float*)d_in[0];   // (B,L,C)
    const float* Wqkv = (const float*)d_in[1];   // (3C,C)
    const float* Wout = (const float*)d_in[2];   // (C,C)
    float* out = (float*)d_out;                  // (B,L,C) fp32

    char* ws = (char*)d_ws;
    const size_t MiB = 1024ull * 1024ull;
    bf16* Xb   = (bf16*)(ws + 0);                // 16 MiB
    bf16* QK   = (bf16*)(ws + 16 * MiB);         // 32 MiB (q cols 0..1023, k cols 1024..2047)
    bf16* VWT  = (bf16*)(ws + 48 * MiB);         // 16 MiB (1024 x 8192, ld 8192)
    bf16* Sbuf = (bf16*)(ws + 64 * MiB);         // 32 MiB (P in place)
    bf16* Wqkb = (bf16*)(ws + 96 * MiB);         // 4 MiB
    bf16* WvT  = (bf16*)(ws + 100 * MiB);        // 2 MiB
    bf16* Wob  = (bf16*)(ws + 102 * MiB);        // 2 MiB
    bf16* W2   = (bf16*)(ws + 104 * MiB);        // 2 MiB  (total 106 MiB)

    cast_all<<<dim3(12288), 256, 0, stream>>>(X, Wqkv, Wout, Xb, Wqkb, Wob, WvT);

    g1_w2_qk<<<dim3(1088), 256, 0, stream>>>(Xb, Wqkb, Wob, WvT, QK, W2);

    g2_vwt_s<<<dim3(1056), 256, 0, stream>>>(W2, Xb, QK, VWT, Sbuf);

    softmax_causal<<<dim3(Bn * Ln / 4), 256, 0, stream>>>(Sbuf);

    g3_out<<<dim3(512), 256, 0, stream>>>(Sbuf, VWT, out);
}